// Round 4
// baseline (36.991 us; speedup 1.0000x reference)
//
#include <hip/hip_runtime.h>
#include <stdint.h>

#define NBOX 8192

// ws layout: float4 sbox[8192] (128 KB) then uint32_t flags[256] (1 KB).

// ---------------------------------------------------------------------------
// Kernel 1: stable rank by (desc score, asc index); scatter boxes as float4
// into sorted order; block 0 zeroes the suppress-flag bitmap.
// key = (~score_bits << 32) | index  -> ascending u64 == desired order.
// ---------------------------------------------------------------------------
__global__ __launch_bounds__(256) void nms_rank_kernel(
    const float4* __restrict__ bbox, const float* __restrict__ score,
    float4* __restrict__ sbox, uint32_t* __restrict__ flags)
{
    __shared__ uint64_t keys[NBOX];          // 64 KB
    const int t = threadIdx.x;
    if (blockIdx.x == 0) flags[t] = 0;       // 256 words

    #pragma unroll
    for (int s = 0; s < NBOX / 256; ++s) {
        int i = t + s * 256;
        uint32_t b = __float_as_uint(score[i]);   // scores in [0,1): bits monotone
        keys[i] = ((uint64_t)(b ^ 0xFFFFFFFFu) << 32) | (uint32_t)i;
    }
    __syncthreads();

    const int e = blockIdx.x * 16 + (t >> 4);  // element this 16-thread group owns
    const int p = t & 15;
    const uint64_t myk = keys[e];
    int cnt = 0;
    // interleaved slices: contiguous 128B per wave-iter, broadcast across same-p
    #pragma unroll 8
    for (int s = 0; s < NBOX / 16; ++s)
        cnt += (keys[s * 16 + p] < myk) ? 1 : 0;

    cnt += __shfl_down(cnt, 8, 16);
    cnt += __shfl_down(cnt, 4, 16);
    cnt += __shfl_down(cnt, 2, 16);
    cnt += __shfl_down(cnt, 1, 16);

    if (p == 0) sbox[cnt] = bbox[e];           // unique rank, one dwordx4 store
}

// ---------------------------------------------------------------------------
// Kernel 2: suppression. Wave task = (jg: 8 sorted rows) x (is: 512-wide
// i-slice). Block's 4 waves share the i-slice (L1 reuse). Register-double-
// buffered prefetch. Hot loop is branch-free: per pair only `inter` vs the
// precomputed threshold 0.4110*ia + 0.4110*ja (conservative for IoU>0.7,
// since union >= 256 and 0.4110 < 0.7/1.7*(1-3e-7)); candidates accumulate
// via __any into a wave-uniform flag -> ONE branch per 64x8 chunk; the exact
// IEEE-f32 reference arithmetic (incl. division) runs only on that rare path.
// ---------------------------------------------------------------------------
__global__ __launch_bounds__(256) void nms_suppress_kernel(
    const float4* __restrict__ sbox, uint32_t* __restrict__ flags)
{
    const int w    = (int)(threadIdx.x >> 6);
    const int lane = (int)(threadIdx.x & 63);
    const int is   = (int)(blockIdx.x >> 8);            // 0..15
    const int jg   = ((int)(blockIdx.x & 255)) * 4 + w; // 0..1023
    const int j0   = jg * 8;
    const int s0   = is * 512;
    if (s0 >= j0 + 7) return;                 // slice entirely above diagonal

    int nfull = (j0 - s0) >> 6;               // chunks with all i < j0
    if (nfull > 8) nfull = 8;
    const int pc = nfull;                      // diagonal (masked) chunk index
    const bool partial = (pc < 8) && (s0 + pc * 64 < j0 + 7);

    float jy1[8], jx1[8], jy2[8], jx2[8], ja[8], tk[8];
    #pragma unroll
    for (int k = 0; k < 8; ++k) {
        float4 b = sbox[j0 + k];
        jy1[k] = b.x; jx1[k] = b.y; jy2[k] = b.z; jx2[k] = b.w;
        ja[k] = (b.z - b.x) * (b.w - b.y);     // same fp op order as reference
        tk[k] = 0.4110f * ja[k];
    }

    uint32_t hit = 0;
    float4 cur = sbox[s0 + lane];              // chunk 0 (in-bounds always)

    for (int c = 0; c < nfull; ++c) {
        // prefetch chunk c+1: s0+(c+1)*64 is a 64-multiple <= j0 <= 8184,
        // hence <= 8128, so index <= 8191: in-bounds.
        float4 nxt = sbox[s0 + (c + 1) * 64 + lane];

        const float iy1 = cur.x, ix1 = cur.y, iy2 = cur.z, ix2 = cur.w;
        const float ia  = (iy2 - iy1) * (ix2 - ix1);
        const float tia = 0.4110f * ia;

        int cand = 0;
        #pragma unroll
        for (int k = 0; k < 8; ++k) {
            float ty1 = fmaxf(iy1, jy1[k]);
            float tx1 = fmaxf(ix1, jx1[k]);
            float ty2 = fminf(iy2, jy2[k]);
            float tx2 = fminf(ix2, jx2[k]);
            float ih = fmaxf(ty2 - ty1, 0.0f);
            float iw = fmaxf(tx2 - tx1, 0.0f);
            float inter = ih * iw;
            cand |= __any(inter > tia + tk[k]);   // v_cmp + scalar or: no branch
        }
        if (cand) {                            // rare: exact reference math
            #pragma unroll
            for (int k = 0; k < 8; ++k) {
                float ty1 = fmaxf(iy1, jy1[k]);
                float tx1 = fmaxf(ix1, jx1[k]);
                float ty2 = fminf(iy2, jy2[k]);
                float tx2 = fminf(ix2, jx2[k]);
                float ih = fmaxf(ty2 - ty1, 0.0f);
                float iw = fmaxf(tx2 - tx1, 0.0f);
                float inter = ih * iw;
                float s  = ia + ja[k];
                float un = s - inter;          // fl(fl(ai+aj)-inter), as ref
                float iou = inter / fmaxf(un, 1e-9f);
                if (iou > 0.7f) hit |= (1u << k);
            }
        }
        cur = nxt;
    }

    if (partial) {                             // cur holds chunk pc
        const int i = s0 + pc * 64 + lane;     // <= 8191 (64-aligned base <= 8128)
        const float iy1 = cur.x, ix1 = cur.y, iy2 = cur.z, ix2 = cur.w;
        const float ia  = (iy2 - iy1) * (ix2 - ix1);
        const float tia = 0.4110f * ia;

        int cand = 0;
        #pragma unroll
        for (int k = 0; k < 8; ++k) {
            float ty1 = fmaxf(iy1, jy1[k]);
            float tx1 = fmaxf(ix1, jx1[k]);
            float ty2 = fminf(iy2, jy2[k]);
            float tx2 = fminf(ix2, jx2[k]);
            float ih = fmaxf(ty2 - ty1, 0.0f);
            float iw = fmaxf(tx2 - tx1, 0.0f);
            float inter = ih * iw;
            cand |= __any((i < j0 + k) & (inter > tia + tk[k]));
        }
        if (cand) {
            #pragma unroll
            for (int k = 0; k < 8; ++k) {
                float ty1 = fmaxf(iy1, jy1[k]);
                float tx1 = fmaxf(ix1, jx1[k]);
                float ty2 = fminf(iy2, jy2[k]);
                float tx2 = fminf(ix2, jx2[k]);
                float ih = fmaxf(ty2 - ty1, 0.0f);
                float iw = fmaxf(tx2 - tx1, 0.0f);
                float inter = ih * iw;
                float s  = ia + ja[k];
                float un = s - inter;
                float iou = inter / fmaxf(un, 1e-9f);
                if ((i < j0 + k) & (iou > 0.7f)) hit |= (1u << k);
            }
        }
    }

    uint32_t byte = 0;
    #pragma unroll
    for (int k = 0; k < 8; ++k)
        if (__any(hit & (1u << k))) byte |= (1u << k);
    if (lane == 0 && byte)
        atomicOr(&flags[jg >> 2], byte << ((jg & 3) * 8));
}

// ---------------------------------------------------------------------------
// Kernel 3: masked float4 write of sorted boxes.
// ---------------------------------------------------------------------------
__global__ __launch_bounds__(256) void nms_write_kernel(
    const float4* __restrict__ sbox, const uint32_t* __restrict__ flags,
    float4* __restrict__ out)
{
    int j = blockIdx.x * 256 + threadIdx.x;
    bool sup = (flags[j >> 5] >> (j & 31)) & 1u;
    float4 v = sbox[j];
    if (sup) { v.x = 0.0f; v.y = 0.0f; v.z = 0.0f; v.w = 0.0f; }
    out[j] = v;
}

extern "C" void kernel_launch(void* const* d_in, const int* in_sizes, int n_in,
                              void* d_out, int out_size, void* d_ws, size_t ws_size,
                              hipStream_t stream) {
    const float4* bbox  = (const float4*)d_in[0];   // (8192,4) f32
    const float*  score = (const float*)d_in[1];    // (8192,)  f32
    float4* out = (float4*)d_out;                   // (8192,4) f32
    float4* sbox = (float4*)d_ws;                   // 128 KB
    uint32_t* flags = (uint32_t*)((float*)d_ws + 4 * NBOX);  // 1 KB

    hipLaunchKernelGGL(nms_rank_kernel, dim3(NBOX / 16), dim3(256), 0, stream,
                       bbox, score, sbox, flags);
    // 16 i-slices x 256 jg-quads = 4096 blocks; block's 4 waves share a slice
    hipLaunchKernelGGL(nms_suppress_kernel, dim3(4096), dim3(256), 0, stream,
                       sbox, flags);
    hipLaunchKernelGGL(nms_write_kernel, dim3(NBOX / 256), dim3(256), 0, stream,
                       sbox, flags, out);
}